// Round 16
// baseline (291.987 us; speedup 1.0000x reference)
//
#include <hip/hip_runtime.h>
#include <hip/hip_bf16.h>

#define B_ROWS 131072
#define H 128
#define SLAB 32
#define NSLAB 8                  // 256 rows per block strip
#define NBLK 512

typedef __bf16 bf16x8 __attribute__((ext_vector_type(8)));
typedef float f32x4 __attribute__((ext_vector_type(4)));

#define LOG2E 1.4426950408889634f

__device__ __forceinline__ float fast_sigmoid(float v) {
    return __builtin_amdgcn_rcpf(1.0f + __builtin_amdgcn_exp2f(-LOG2E * v));
}
__device__ __forceinline__ float fast_tanh(float v) {
    return 1.0f - 2.0f * __builtin_amdgcn_rcpf(1.0f + __builtin_amdgcn_exp2f(2.0f * LOG2E * v));
}

struct WPtrs {
    const float* wx[4];
    const float* wh[4];
    const float* bx[4];
    const float* bh[4];
};

// Wcat[n][k]: n = gate*128 + unit, k in [0,256) = [X-k | h-k]. bsum[n] = bx+bh.
__global__ __launch_bounds__(256) void prep_weights(WPtrs p, __bf16* __restrict__ wcat,
                                                    float* __restrict__ bsum) {
    int n = blockIdx.x;
    int k = threadIdx.x;
    int g = n >> 7, r = n & 127;
    float v = (k < H) ? p.wx[g][r * H + k] : p.wh[g][r * H + (k - H)];
    wcat[n * 256 + k] = (__bf16)v;
    if (k == 0) bsum[n] = p.bx[g][r] + p.bh[g][r];
}

// R16: SWAPPED MFMA OPERANDS (W as A, x as B) -> D[unit][brow]: each lane holds
// 4 CONSECUTIVE units (reg idx) of one batch row (col=lane&15). cp loads and
// h/c stores become float4 (16B granules, 64B contiguous per 16-lane group):
// ~4x fewer TA-issue slots than the old scattered-4B epilogue, which costed
// ~3000 of the 6650-cyc cadence (the R11..R13 plateau). Skeleton = R12's
// proven RA/RB macro ping-pong (R15's rolled loop collapsed to VGPR=76).
__global__ __launch_bounds__(512, 1) void lstm_fused(
    const float* __restrict__ X, const float* __restrict__ Hp, const float* __restrict__ Cp,
    const __bf16* __restrict__ Wcat, const float* __restrict__ Bsum,
    float* __restrict__ out)
{
    __shared__ char abuf[2][SLAB * 512];    // 2 x 16 KB bf16 [X|h] slab, XOR-swizzled

    const int t = threadIdx.x;
    const int lane = t & 63;
    const int wv = t >> 6;                  // 0..7
    const int rg = wv >> 2;                 // 0..1: batch-row group (rg*16 within slab)
    const int ug = wv & 3;                  // 0..3: unit group (ug*32)
    const int l16 = lane & 15;              // batch row within group (B-operand col)
    const int kg = lane >> 4;               // 0..3
    const long base = (long)blockIdx.x * (SLAB * NSLAB);
    const long c_off = (long)B_ROWS * H;

    // W fragment base (A-operand): unit row = ug*32 + ut*16 + l16, k = kc*32 + kg*8
    const __bf16* wbase = Wcat + ((long)(ug * 32 + l16)) * 256 + kg * 8;
    const int ubase = ug * 32 + kg * 4;     // lane's first unit in epilogue (per ut: +ut*16)

    // per-lane bias: gates x ut x 4 consecutive units
    f32x4 bias4[4][2];
#pragma unroll
    for (int g = 0; g < 4; ++g)
#pragma unroll
        for (int ut = 0; ut < 2; ++ut)
            bias4[g][ut] = *(const f32x4*)(Bsum + g * H + ubase + ut * 16);

    // staging map: thread t -> rows {t>>5, 16+(t>>5)}, 32B chunk t&31 (0..15 X, 16..31 h)
    const int s_r = t >> 5;
    const int s_g8 = t & 31;

    auto stage_load = [&](float4* L, long srow) {
#pragma unroll
        for (int q = 0; q < 2; ++q) {
            int row = q * 16 + s_r;
            const float* sp = (s_g8 < 16) ? (X + (srow + row) * H + s_g8 * 8)
                                          : (Hp + (srow + row) * H + (s_g8 - 16) * 8);
            L[q * 2]     = *(const float4*)sp;
            L[q * 2 + 1] = *(const float4*)(sp + 4);
        }
    };
    auto write_slab = [&](char* buf, const float4* W) {
#pragma unroll
        for (int q = 0; q < 2; ++q) {
            int row = q * 16 + s_r;
            union { __bf16 e[8]; bf16x8 v; } u;
            float4 lo = W[q * 2], hi = W[q * 2 + 1];
            u.e[0] = (__bf16)lo.x; u.e[1] = (__bf16)lo.y;
            u.e[2] = (__bf16)lo.z; u.e[3] = (__bf16)lo.w;
            u.e[4] = (__bf16)hi.x; u.e[5] = (__bf16)hi.y;
            u.e[6] = (__bf16)hi.z; u.e[7] = (__bf16)hi.w;
            *(bf16x8*)(buf + row * 512 + ((s_g8 ^ (row & 7)) << 4)) = u.v;
        }
    };
    auto load_cp = [&](f32x4* c, long srow) {
        const float* cb = Cp + (srow + rg * 16 + l16) * (long)H + ubase;
#pragma unroll
        for (int ut = 0; ut < 2; ++ut)
            c[ut] = *(const f32x4*)(cb + ut * 16);
    };

    float4 RA[4], RB[4];
    f32x4 cpv[2], cpn[2];

    // prologue: slab0 -> buf0; slab1 loads in flight
    stage_load(RB, base);
    load_cp(cpv, base);
    stage_load(RA, base + SLAB);
    write_slab(abuf[0], RB);                // auto vmcnt wait on RB only

#define BODY(S, W, L, BW, BC) {                                                   \
    const long srow = base + (long)(S) * SLAB;                                    \
    const long pn1 = ((S) + 1 < NSLAB) ? (S) + 1 : NSLAB - 1;                     \
    const long pn2 = ((S) + 2 < NSLAB) ? (S) + 2 : NSLAB - 1;                     \
    stage_load(L, base + pn2 * SLAB);                                             \
    load_cp(cpn, base + pn1 * SLAB);                                              \
    asm volatile("s_waitcnt lgkmcnt(0)\n\ts_barrier" ::: "memory");               \
    write_slab(abuf[BW], W);                                                      \
    const char* ac = abuf[BC];                                                    \
    f32x4 acc[4][2] = {};                                                         \
    const int arow = rg * 16 + l16;                                               \
    _Pragma("unroll")                                                             \
    for (int kc = 0; kc < 8; ++kc) {                                              \
        bf16x8 xf = *(const bf16x8*)(ac + arow * 512 + (((kc * 4 + kg) ^ (arow & 7)) << 4)); \
        _Pragma("unroll")                                                         \
        for (int g = 0; g < 4; ++g) {                                             \
            _Pragma("unroll")                                                     \
            for (int ut = 0; ut < 2; ++ut) {                                      \
                bf16x8 wf = *(const bf16x8*)(wbase + (g * 128 + ut * 16) * 256 + kc * 32); \
                acc[g][ut] = __builtin_amdgcn_mfma_f32_16x16x32_bf16(wf, xf, acc[g][ut], 0, 0, 0); \
            }                                                                     \
        }                                                                         \
    }                                                                             \
    const long brow = srow + rg * 16 + l16;                                       \
    _Pragma("unroll")                                                             \
    for (int ut = 0; ut < 2; ++ut) {                                              \
        f32x4 hv, cv;                                                             \
        _Pragma("unroll")                                                         \
        for (int r = 0; r < 4; ++r) {                                             \
            float fg = acc[0][ut][r] + bias4[0][ut][r];                           \
            float ig = acc[1][ut][r] + bias4[1][ut][r];                           \
            float cg = acc[2][ut][r] + bias4[2][ut][r];                           \
            float og = acc[3][ut][r] + bias4[3][ut][r];                           \
            float ft = fast_sigmoid(fg);                                          \
            float it = fast_sigmoid(ig);                                          \
            float cc = fast_tanh(cg);                                             \
            float ot = fast_sigmoid(og);                                          \
            float ct = ft * cpv[ut][r] + it * cc;                                 \
            float ht = ot * fast_tanh(ct);                                        \
            hv[r] = ht;                                                           \
            cv[r] = ct;                                                           \
        }                                                                         \
        *(f32x4*)(out + brow * H + ubase + ut * 16) = hv;                         \
        *(f32x4*)(out + c_off + brow * H + ubase + ut * 16) = cv;                 \
    }                                                                             \
    cpv[0] = cpn[0]; cpv[1] = cpn[1];                                             \
}

    for (int sp = 0; sp < NSLAB / 2; ++sp) {
        BODY(2 * sp,     RA, RB, 1, 0);     // write buf1 (slab 2sp+1), compute buf0
        BODY(2 * sp + 1, RB, RA, 0, 1);     // write buf0 (slab 2sp+2), compute buf1
    }
#undef BODY
}

extern "C" void kernel_launch(void* const* d_in, const int* in_sizes, int n_in,
                              void* d_out, int out_size, void* d_ws, size_t ws_size,
                              hipStream_t stream) {
    const float* X  = (const float*)d_in[0];
    const float* Hp = (const float*)d_in[1];
    const float* Cp = (const float*)d_in[2];
    WPtrs p;
    p.wx[0] = (const float*)d_in[3];  p.bx[0] = (const float*)d_in[4];
    p.wh[0] = (const float*)d_in[5];  p.bh[0] = (const float*)d_in[6];
    p.wx[1] = (const float*)d_in[7];  p.bx[1] = (const float*)d_in[8];
    p.wh[1] = (const float*)d_in[9];  p.bh[1] = (const float*)d_in[10];
    p.wx[2] = (const float*)d_in[11]; p.bx[2] = (const float*)d_in[12];
    p.wh[2] = (const float*)d_in[13]; p.bh[2] = (const float*)d_in[14];
    p.wx[3] = (const float*)d_in[15]; p.bx[3] = (const float*)d_in[16];
    p.wh[3] = (const float*)d_in[17]; p.bh[3] = (const float*)d_in[18];

    __bf16* wcat = (__bf16*)d_ws;
    float*  bsum = (float*)((char*)d_ws + 512 * 256 * 2);

    prep_weights<<<512, 256, 0, stream>>>(p, wcat, bsum);
    lstm_fused<<<NBLK, 512, 0, stream>>>(X, Hp, Cp, wcat, bsum, (float*)d_out);
}

// Round 17
// 134.672 us; speedup vs baseline: 2.1681x; 2.1681x over previous
//
#include <hip/hip_runtime.h>
#include <hip/hip_bf16.h>

#define B_ROWS 131072
#define H 128
#define SLAB 16
#define NSLAB 16                 // 256 rows per strip
#define NBLK 2048                // 512 strips x 4 unit-quarters

typedef __bf16 bf16x8 __attribute__((ext_vector_type(8)));
typedef float f32x4 __attribute__((ext_vector_type(4)));

#define LOG2E 1.4426950408889634f

__device__ __forceinline__ float fast_sigmoid(float v) {
    return __builtin_amdgcn_rcpf(1.0f + __builtin_amdgcn_exp2f(-LOG2E * v));
}
__device__ __forceinline__ float fast_tanh(float v) {
    return 1.0f - 2.0f * __builtin_amdgcn_rcpf(1.0f + __builtin_amdgcn_exp2f(2.0f * LOG2E * v));
}

struct WPtrs {
    const float* wx[4];
    const float* wh[4];
    const float* bx[4];
    const float* bh[4];
};

// NEW layout: Wcat2[n2][k], n2 = unit*4 + gate (gate: 0=f,1=i,2=c,3=o), k=[X|h].
// bsum[n2] likewise. This makes B-fragment col packing (unit,gate) contiguous.
__global__ __launch_bounds__(256) void prep_weights(WPtrs p, __bf16* __restrict__ wcat,
                                                    float* __restrict__ bsum) {
    int n2 = blockIdx.x;         // 0..511
    int k = threadIdx.x;         // 0..255
    int g = n2 & 3, u = n2 >> 2;
    float v = (k < H) ? p.wx[g][u * H + k] : p.wh[g][u * H + (k - H)];
    wcat[n2 * 256 + k] = (__bf16)v;
    if (k == 0) bsum[n2] = p.bx[g][u] + p.bh[g][u];
}

// R17: 8 units/wave -> weight frags = 64 VGPR, pinned. Per kc: 1 ds_read (A) +
// 2 MFMA (B cols = 8 units x gate-pair, col=2u+g'). Gates of unit u land on
// lane pair (2u,2u+1); one shfl_xor(1) regroups -> epilogue lane-local.
// Block 256 thr = 4 waves = 32 units; 2048 blocks; quarter-siblings (same Bk&7)
// share XCD L2 for the A re-reads. (256,3): VGPR cap ~170, use ~140 -> 3 blk/CU.
// cp loaded FIRST in body: oldest in vmcnt FIFO, its wait never drains stage.
__global__ __launch_bounds__(256, 3) void lstm_fused(
    const float* __restrict__ X, const float* __restrict__ Hp, const float* __restrict__ Cp,
    const __bf16* __restrict__ Wcat2, const float* __restrict__ Bsum,
    float* __restrict__ out)
{
    __shared__ char abuf[2][SLAB * 512];    // 2 x 8 KB bf16 [X|h] slab, XOR-swizzled

    const int t = threadIdx.x;
    const int lane = t & 63;
    const int wv = t >> 6;                  // 0..3: unit group of 8
    const int l16 = lane & 15;
    const int kg = lane >> 4;               // 0..3
    const int Bk = blockIdx.x;
    const int uq = (Bk >> 3) & 3;           // unit quarter
    const int rb = (Bk & 7) | ((Bk >> 5) << 3);   // 0..511 row strip
    const long base = (long)rb * (SLAB * NSLAB);
    const long c_off = (long)B_ROWS * H;
    const int unit = uq * 32 + wv * 8 + (l16 >> 1);   // this lane's unit
    const int gp = l16 & 1;                 // gate-pair member

    // ---- B frags -> 64 VGPR, pinned ----
    bf16x8 wreg[2][8];
#pragma unroll
    for (int t2 = 0; t2 < 2; ++t2) {
        const __bf16* wb = Wcat2 + ((long)(unit * 4 + 2 * t2 + gp)) * 256 + kg * 8;
#pragma unroll
        for (int kc = 0; kc < 8; ++kc) {
            wreg[t2][kc] = *(const bf16x8*)(wb + kc * 32);
            asm volatile("" : "+v"(wreg[t2][kc]));
        }
    }
    float bias2[2];
#pragma unroll
    for (int t2 = 0; t2 < 2; ++t2) bias2[t2] = Bsum[unit * 4 + 2 * t2 + gp];

    // staging map: thread t -> row t>>4 (0..15), 16-bf16 chunk t&15 (0..7 X, 8..15 h)
    const int s_r = t >> 4;
    const int s_c = t & 15;

    auto stage_load = [&](float4* L, long srow) {
        const float* sp = (s_c < 8) ? (X + (srow + s_r) * H + s_c * 16)
                                    : (Hp + (srow + s_r) * H + (s_c - 8) * 16);
        L[0] = *(const float4*)sp;
        L[1] = *(const float4*)(sp + 4);
        L[2] = *(const float4*)(sp + 8);
        L[3] = *(const float4*)(sp + 12);
    };
    auto write_slab = [&](char* buf, const float4* W) {
#pragma unroll
        for (int hh = 0; hh < 2; ++hh) {
            union { __bf16 e[8]; bf16x8 v; } u;
            float4 lo = W[hh * 2], hi = W[hh * 2 + 1];
            u.e[0] = (__bf16)lo.x; u.e[1] = (__bf16)lo.y;
            u.e[2] = (__bf16)lo.z; u.e[3] = (__bf16)lo.w;
            u.e[4] = (__bf16)hi.x; u.e[5] = (__bf16)hi.y;
            u.e[6] = (__bf16)hi.z; u.e[7] = (__bf16)hi.w;
            int sl = s_c * 2 + hh;          // 16B slot 0..31
            *(bf16x8*)(buf + s_r * 512 + ((sl ^ (s_r & 7)) << 4)) = u.v;
        }
    };

    float4 RA[4], RB[4];
    float cpv[4];

    // prologue: slab0 -> buf0; slab1 loads in flight
    stage_load(RB, base);
    write_slab(abuf[0], RB);                // exact vmcnt wait on RB only
    stage_load(RA, base + SLAB);

#define BODY(S, W, L, BW, BC) {                                                   \
    const long srow = base + (long)(S) * SLAB;                                    \
    _Pragma("unroll")                                                             \
    for (int r = 0; r < 4; ++r)                                                   \
        cpv[r] = Cp[(srow + kg * 4 + r) * (long)H + unit];                        \
    const long pn2 = ((S) + 2 < NSLAB) ? (S) + 2 : NSLAB - 1;                     \
    stage_load(L, base + pn2 * SLAB);                                             \
    asm volatile("s_waitcnt lgkmcnt(0)\n\ts_barrier" ::: "memory");               \
    write_slab(abuf[BW], W);                                                      \
    const char* ac = abuf[BC];                                                    \
    f32x4 acc[2] = {};                                                            \
    _Pragma("unroll")                                                             \
    for (int kc = 0; kc < 8; ++kc) {                                              \
        int slot = ((kc * 4 + kg) ^ (l16 & 7)) << 4;                              \
        bf16x8 av = *(const bf16x8*)(ac + l16 * 512 + slot);                      \
        acc[0] = __builtin_amdgcn_mfma_f32_16x16x32_bf16(av, wreg[0][kc], acc[0], 0, 0, 0); \
        acc[1] = __builtin_amdgcn_mfma_f32_16x16x32_bf16(av, wreg[1][kc], acc[1], 0, 0, 0); \
    }                                                                             \
    _Pragma("unroll")                                                             \
    for (int r = 0; r < 4; ++r) { acc[0][r] += bias2[0]; acc[1][r] += bias2[1]; } \
    f32x4 sh0, sh1;                                                               \
    _Pragma("unroll")                                                             \
    for (int r = 0; r < 4; ++r) {                                                 \
        sh0[r] = __shfl_xor(acc[0][r], 1);                                        \
        sh1[r] = __shfl_xor(acc[1][r], 1);                                        \
    }                                                                             \
    const bool oddl = lane & 1;                                                   \
    _Pragma("unroll")                                                             \
    for (int r = 0; r < 4; ++r) {                                                 \
        float fg = oddl ? sh0[r] : acc[0][r];                                     \
        float ig = oddl ? acc[0][r] : sh0[r];                                     \
        float cg = oddl ? sh1[r] : acc[1][r];                                     \
        float og = oddl ? acc[1][r] : sh1[r];                                     \
        float ft = fast_sigmoid(fg);                                              \
        float it = fast_sigmoid(ig);                                              \
        float cc = fast_tanh(cg);                                                 \
        float ot = fast_sigmoid(og);                                              \
        float ct = ft * cpv[r] + it * cc;                                         \
        float ht = ot * fast_tanh(ct);                                            \
        long row = srow + kg * 4 + r;                                             \
        float* dst = oddl ? (out + c_off + row * H + unit) : (out + row * H + unit); \
        *dst = oddl ? ct : ht;                                                    \
    }                                                                             \
}

    for (int sp = 0; sp < NSLAB / 2; ++sp) {
        BODY(2 * sp,     RA, RB, 1, 0);     // write buf1 (slab 2sp+1), compute buf0
        BODY(2 * sp + 1, RB, RA, 0, 1);     // write buf0 (slab 2sp+2), compute buf1
    }
#undef BODY
}

extern "C" void kernel_launch(void* const* d_in, const int* in_sizes, int n_in,
                              void* d_out, int out_size, void* d_ws, size_t ws_size,
                              hipStream_t stream) {
    const float* X  = (const float*)d_in[0];
    const float* Hp = (const float*)d_in[1];
    const float* Cp = (const float*)d_in[2];
    WPtrs p;
    p.wx[0] = (const float*)d_in[3];  p.bx[0] = (const float*)d_in[4];
    p.wh[0] = (const float*)d_in[5];  p.bh[0] = (const float*)d_in[6];
    p.wx[1] = (const float*)d_in[7];  p.bx[1] = (const float*)d_in[8];
    p.wh[1] = (const float*)d_in[9];  p.bh[1] = (const float*)d_in[10];
    p.wx[2] = (const float*)d_in[11]; p.bx[2] = (const float*)d_in[12];
    p.wh[2] = (const float*)d_in[13]; p.bh[2] = (const float*)d_in[14];
    p.wx[3] = (const float*)d_in[15]; p.bx[3] = (const float*)d_in[16];
    p.wh[3] = (const float*)d_in[17]; p.bh[3] = (const float*)d_in[18];

    __bf16* wcat = (__bf16*)d_ws;
    float*  bsum = (float*)((char*)d_ws + 512 * 256 * 2);

    prep_weights<<<512, 256, 0, stream>>>(p, wcat, bsum);
    lstm_fused<<<NBLK, 256, 0, stream>>>(X, Hp, Cp, wcat, bsum, (float*)d_out);
}

// Round 18
// 96.931 us; speedup vs baseline: 3.0123x; 1.3894x over previous
//
#include <hip/hip_runtime.h>
#include <hip/hip_bf16.h>

#define B_ROWS 131072
#define H 128
#define SLAB 16
#define NSLAB 16                 // 256 rows per block strip
#define NBLK 512

typedef __bf16 bf16x8 __attribute__((ext_vector_type(8)));
typedef float f32x4 __attribute__((ext_vector_type(4)));

#define LOG2E 1.4426950408889634f

__device__ __forceinline__ float fast_sigmoid(float v) {
    return __builtin_amdgcn_rcpf(1.0f + __builtin_amdgcn_exp2f(-LOG2E * v));
}
__device__ __forceinline__ float fast_tanh(float v) {
    return 1.0f - 2.0f * __builtin_amdgcn_rcpf(1.0f + __builtin_amdgcn_exp2f(2.0f * LOG2E * v));
}

struct WPtrs {
    const float* wx[4];
    const float* wh[4];
    const float* bx[4];
    const float* bh[4];
};

// Wcat[n][k]: n = gate*128 + unit, k in [0,256) = [X-k | h-k]. bsum[n] = bx+bh.
__global__ __launch_bounds__(256) void prep_weights(WPtrs p, __bf16* __restrict__ wcat,
                                                    float* __restrict__ bsum) {
    int n = blockIdx.x;
    int k = threadIdx.x;
    int g = n >> 7, r = n & 127;
    float v = (k < H) ? p.wx[g][r * H + k] : p.wh[g][r * H + (k - H)];
    wcat[n * 256 + k] = (__bf16)v;
    if (k == 0) bsum[n] = p.bx[g][r] + p.bh[g][r];
}

// R18 = R13 (pinned weights -> AGPR, zero in-loop L2 stream) + R16's swapped
// MFMA operands (W as A-operand -> D: row=unit, col=batch row) at FULL geometry
// (8 waves x 16 units x whole slab). Lane holds units kg*4..+3 for batch row
// l16 -> cp/h/c are f32x4 (3 vmem inst/lane/slab vs 24 scattered): kills the
// epilogue TA saturation (R13's limiter). Weights pinned kill the L2 stream
// (R11's limiter). Both ~60-90us serial costs removed together.
__global__ __launch_bounds__(512, 1) void lstm_fused(
    const float* __restrict__ X, const float* __restrict__ Hp, const float* __restrict__ Cp,
    const __bf16* __restrict__ Wcat, const float* __restrict__ Bsum,
    float* __restrict__ out)
{
    __shared__ char abuf[2][SLAB * 512];    // 2 x 8 KB bf16 [X|h] slab, XOR-swizzled

    const int t = threadIdx.x;
    const int lane = t & 63;
    const int wv = t >> 6;                  // 0..7: unit group of 16
    const int l16 = lane & 15;              // batch row within slab / W unit-row
    const int kg = lane >> 4;               // 0..3
    const long base = (long)blockIdx.x * (SLAB * NSLAB);
    const long c_off = (long)B_ROWS * H;
    const int ubase = wv * 16 + kg * 4;     // lane's 4 consecutive units (epilogue)

    // ---- W fragments (A-operand role): unit row = wv*16 + l16, k = kc*32+kg*8 ----
    bf16x8 wreg[4][8];                      // 128 regs, pinned -> AGPR (R13 mechanism)
    {
        const __bf16* wb = Wcat + ((long)(wv * 16 + l16)) * 256 + kg * 8;
#pragma unroll
        for (int g = 0; g < 4; ++g)
#pragma unroll
            for (int kc = 0; kc < 8; ++kc) {
                wreg[g][kc] = *(const bf16x8*)(wb + g * (128 * 256) + kc * 32);
                asm volatile("" : "+v"(wreg[g][kc]));
            }
    }
    f32x4 bias4[4];
#pragma unroll
    for (int g = 0; g < 4; ++g)
        bias4[g] = *(const f32x4*)(Bsum + g * H + ubase);

    // staging map: thread t -> row t>>5 (0..15), 8-float group t&31 (0..15 X, 16..31 h)
    const int s_r = t >> 5;
    const int s_g8 = t & 31;

    auto stage_load = [&](float4* L, long srow) {
        const float* sp = (s_g8 < 16) ? (X + (srow + s_r) * H + s_g8 * 8)
                                      : (Hp + (srow + s_r) * H + (s_g8 - 16) * 8);
        L[0] = *(const float4*)sp;
        L[1] = *(const float4*)(sp + 4);
    };
    auto write_slab = [&](char* buf, const float4* W) {
        union { __bf16 e[8]; bf16x8 v; } u;
        float4 lo = W[0], hi = W[1];
        u.e[0] = (__bf16)lo.x; u.e[1] = (__bf16)lo.y;
        u.e[2] = (__bf16)lo.z; u.e[3] = (__bf16)lo.w;
        u.e[4] = (__bf16)hi.x; u.e[5] = (__bf16)hi.y;
        u.e[6] = (__bf16)hi.z; u.e[7] = (__bf16)hi.w;
        *(bf16x8*)(buf + s_r * 512 + ((s_g8 ^ (s_r & 7)) << 4)) = u.v;
    };
    auto load_cp = [&](f32x4* c, long srow) {
        *c = *(const f32x4*)(Cp + (srow + l16) * (long)H + ubase);
    };

    float4 RA[2], RB[2];
    f32x4 cpv, cpn;

    // prologue: slab0 -> buf0; slab1 loads in flight
    stage_load(RB, base);
    load_cp(&cpv, base);
    stage_load(RA, base + SLAB);
    write_slab(abuf[0], RB);                // exact vmcnt wait on RB only

#define BODY(S, W, L, BW, BC) {                                                   \
    const long srow = base + (long)(S) * SLAB;                                    \
    const long pn1 = ((S) + 1 < NSLAB) ? (S) + 1 : NSLAB - 1;                     \
    const long pn2 = ((S) + 2 < NSLAB) ? (S) + 2 : NSLAB - 1;                     \
    stage_load(L, base + pn2 * SLAB);                                             \
    load_cp(&cpn, base + pn1 * SLAB);                                             \
    asm volatile("s_waitcnt lgkmcnt(0)\n\ts_barrier" ::: "memory");               \
    write_slab(abuf[BW], W);                                                      \
    const char* ac = abuf[BC];                                                    \
    f32x4 acc[4] = {};                                                            \
    _Pragma("unroll")                                                             \
    for (int kc = 0; kc < 8; ++kc) {                                              \
        int slot = ((kc * 4 + kg) ^ (l16 & 7)) << 4;                              \
        bf16x8 xf = *(const bf16x8*)(ac + l16 * 512 + slot);                      \
        _Pragma("unroll")                                                         \
        for (int g = 0; g < 4; ++g)                                               \
            acc[g] = __builtin_amdgcn_mfma_f32_16x16x32_bf16(wreg[g][kc], xf, acc[g], 0, 0, 0); \
    }                                                                             \
    const long brow = srow + l16;                                                 \
    f32x4 hv, cv;                                                                 \
    _Pragma("unroll")                                                             \
    for (int r = 0; r < 4; ++r) {                                                 \
        float fg = acc[0][r] + bias4[0][r];                                       \
        float ig = acc[1][r] + bias4[1][r];                                       \
        float cg = acc[2][r] + bias4[2][r];                                       \
        float og = acc[3][r] + bias4[3][r];                                       \
        float ft = fast_sigmoid(fg);                                              \
        float it = fast_sigmoid(ig);                                              \
        float cc = fast_tanh(cg);                                                 \
        float ot = fast_sigmoid(og);                                              \
        float ct = ft * cpv[r] + it * cc;                                         \
        float ht = ot * fast_tanh(ct);                                            \
        hv[r] = ht;                                                               \
        cv[r] = ct;                                                               \
    }                                                                             \
    *(f32x4*)(out + brow * H + ubase) = hv;                                       \
    *(f32x4*)(out + c_off + brow * H + ubase) = cv;                               \
    cpv = cpn;                                                                    \
}

    for (int sp = 0; sp < NSLAB / 2; ++sp) {
        BODY(2 * sp,     RA, RB, 1, 0);     // write buf1 (slab 2sp+1), compute buf0
        BODY(2 * sp + 1, RB, RA, 0, 1);     // write buf0 (slab 2sp+2), compute buf1
    }
#undef BODY
}

extern "C" void kernel_launch(void* const* d_in, const int* in_sizes, int n_in,
                              void* d_out, int out_size, void* d_ws, size_t ws_size,
                              hipStream_t stream) {
    const float* X  = (const float*)d_in[0];
    const float* Hp = (const float*)d_in[1];
    const float* Cp = (const float*)d_in[2];
    WPtrs p;
    p.wx[0] = (const float*)d_in[3];  p.bx[0] = (const float*)d_in[4];
    p.wh[0] = (const float*)d_in[5];  p.bh[0] = (const float*)d_in[6];
    p.wx[1] = (const float*)d_in[7];  p.bx[1] = (const float*)d_in[8];
    p.wh[1] = (const float*)d_in[9];  p.bh[1] = (const float*)d_in[10];
    p.wx[2] = (const float*)d_in[11]; p.bx[2] = (const float*)d_in[12];
    p.wh[2] = (const float*)d_in[13]; p.bh[2] = (const float*)d_in[14];
    p.wx[3] = (const float*)d_in[15]; p.bx[3] = (const float*)d_in[16];
    p.wh[3] = (const float*)d_in[17]; p.bh[3] = (const float*)d_in[18];

    __bf16* wcat = (__bf16*)d_ws;
    float*  bsum = (float*)((char*)d_ws + 512 * 256 * 2);

    prep_weights<<<512, 256, 0, stream>>>(p, wcat, bsum);
    lstm_fused<<<NBLK, 512, 0, stream>>>(X, Hp, Cp, wcat, bsum, (float*)d_out);
}